// Round 8
// baseline (133.718 us; speedup 1.0000x reference)
//
#include <hip/hip_runtime.h>
#include <hip/hip_bf16.h>

#define B_ 8
#define C_ 256
#define OC_ 128
#define L_ 4096
#define EPS_ 1e-5f
#define SPLITK 8

typedef unsigned short u16;
typedef __attribute__((ext_vector_type(4))) unsigned short u16x4;
typedef __attribute__((ext_vector_type(8))) unsigned short u16x8;
typedef __attribute__((ext_vector_type(4))) float f32x4;
typedef __attribute__((ext_vector_type(8))) short bf16x8;

__device__ inline u16 f2bf(float f) {
  union { __hip_bfloat16 h; u16 u; } v;
  v.h = __float2bfloat16(f);
  return v.u;
}
__device__ inline float bf2f(u16 u) {
  union { float f; unsigned u; } v;
  v.u = ((unsigned)u) << 16;
  return v.f;
}

__device__ inline void gload_lds16(const void* g, void* lds) {
  __builtin_amdgcn_global_load_lds(
      (const __attribute__((address_space(1))) unsigned int*)g,
      (__attribute__((address_space(3))) unsigned int*)lds, 16, 0, 0);
}

// x -> Xb[b][c][l], XbT[b][l][c] (bf16), + partial row sums spartial[ltile][b*C+c]
// Transpose via stride-65 LDS (odd stride => ~2-way conflicts, free).
__global__ __launch_bounds__(256) void k_cvt(const float* __restrict__ x,
                                             u16* __restrict__ Xb,
                                             u16* __restrict__ XbT,
                                             float* __restrict__ spartial) {
  __shared__ u16 T[64 * 65];   // T[l*65 + c]
  __shared__ float P[64][17];
  const int b = blockIdx.z, c0 = blockIdx.y * 64, l0 = blockIdx.x * 64;
  const int tid = threadIdx.x;
#pragma unroll
  for (int it = 0; it < 4; ++it) {
    int idx = it * 256 + tid;
    int row = idx >> 4;          // c-local
    int col = (idx & 15) << 2;   // l-local
    size_t gi = ((size_t)(b * C_ + c0 + row)) * L_ + l0 + col;
    float4 v = *(const float4*)(x + gi);
    u16 u0 = f2bf(v.x), u1 = f2bf(v.y), u2 = f2bf(v.z), u3 = f2bf(v.w);
    u16x4 u = {u0, u1, u2, u3};
    *(u16x4*)(Xb + gi) = u;
    T[(col + 0) * 65 + row] = u0;
    T[(col + 1) * 65 + row] = u1;
    T[(col + 2) * 65 + row] = u2;
    T[(col + 3) * 65 + row] = u3;
    P[row][idx & 15] = v.x + v.y + v.z + v.w;
  }
  __syncthreads();
  if (tid < 64) {
    float acc = 0.f;
#pragma unroll
    for (int j = 0; j < 16; j++) acc += P[tid][j];
    spartial[(size_t)blockIdx.x * (B_ * C_) + b * C_ + c0 + tid] = acc;
  }
#pragma unroll
  for (int it = 0; it < 4; ++it) {
    int idx = it * 256 + tid;
    int lrow = idx >> 4;         // l-local
    int ccol = (idx & 15) << 2;  // c-local
    u16x4 u = {T[lrow * 65 + ccol], T[lrow * 65 + ccol + 1],
               T[lrow * 65 + ccol + 2], T[lrow * 65 + ccol + 3]};
    *(u16x4*)(XbT + ((size_t)b * L_ + l0 + lrow) * C_ + c0 + ccol) = u;
  }
}

// S[b] = Xb Xb^T via MFMA bf16, split-K, 64x64 tiles, 2-phase dbuf.
// grid: (16, SPLITK, B) = 1024 blocks, 256 thr.
__global__ __launch_bounds__(256) void k_xxt(const u16* __restrict__ Xb,
                                             float* __restrict__ Spart) {
  const int b = blockIdx.z, split = blockIdx.y;
  const int ti = blockIdx.x >> 2, tj = blockIdx.x & 3;
  __shared__ u16 lds[2][2][64 * 64];
  const int tid = threadIdx.x, lane = tid & 63;
  const int wid = tid >> 6, wr = wid >> 1, wc = wid & 1;
  const u16* Arows = Xb + ((size_t)b * C_ + ti * 64) * L_;
  const u16* Brows = Xb + ((size_t)b * C_ + tj * 64) * L_;
  const int k0 = split * (L_ / SPLITK);
  f32x4 acc[2][2] = {};

  auto STAGE = [&](int buf, int kt) {
#pragma unroll
    for (int ch = 0; ch < 2; ch++) {
      int d = ch * 4096 + tid * 16;
      int row = d >> 7;
      int kb = (d & 127) ^ ((row & 7) << 4);
      gload_lds16(Arows + (size_t)row * L_ + k0 + kt + (kb >> 1), (char*)lds[buf][0] + d);
      gload_lds16(Brows + (size_t)row * L_ + k0 + kt + (kb >> 1), (char*)lds[buf][1] + d);
    }
  };

  STAGE(0, 0);
  asm volatile("s_waitcnt vmcnt(0)" ::: "memory");
  __syncthreads();
  int cur = 0;
  for (int kt = 0; kt < L_ / SPLITK; kt += 64) {
    if (kt + 64 < L_ / SPLITK) STAGE(cur ^ 1, kt + 64);
#pragma unroll
    for (int kk = 0; kk < 2; kk++) {
      bf16x8 af[2], bfr[2];
#pragma unroll
      for (int m = 0; m < 2; m++) {
        int row = wr * 32 + m * 16 + (lane & 15);
        int kb = ((kk << 6) + ((lane >> 4) << 4)) ^ ((row & 7) << 4);
        af[m] = *(const bf16x8*)((const char*)lds[cur][0] + row * 128 + kb);
      }
#pragma unroll
      for (int n = 0; n < 2; n++) {
        int row = wc * 32 + n * 16 + (lane & 15);
        int kb = ((kk << 6) + ((lane >> 4) << 4)) ^ ((row & 7) << 4);
        bfr[n] = *(const bf16x8*)((const char*)lds[cur][1] + row * 128 + kb);
      }
#pragma unroll
      for (int m = 0; m < 2; m++)
#pragma unroll
        for (int n = 0; n < 2; n++)
          acc[m][n] = __builtin_amdgcn_mfma_f32_16x16x32_bf16(af[m], bfr[n], acc[m][n], 0, 0, 0);
    }
    asm volatile("s_waitcnt vmcnt(0)" ::: "memory");
    __syncthreads();
    cur ^= 1;
  }
  float* Sp = Spart + ((size_t)split * B_ + b) * C_ * C_;
#pragma unroll
  for (int m = 0; m < 2; m++)
#pragma unroll
    for (int n = 0; n < 2; n++) {
      int r0 = ti * 64 + wr * 32 + m * 16 + ((lane >> 4) << 2);
      int c0 = tj * 64 + wc * 32 + n * 16 + (lane & 15);
#pragma unroll
      for (int r = 0; r < 4; r++)
        Sp[(size_t)(r0 + r) * C_ + c0] = acc[m][n][r];
    }
}

// blocks <2048: S (+ Sb bf16); 2048-2055: s; 2056-2071: gwT = g_w^T
__global__ __launch_bounds__(256) void k_sreduce(const float* __restrict__ Spart,
                                                 const float* __restrict__ spartial,
                                                 const float* __restrict__ g_w,
                                                 float* __restrict__ S,
                                                 u16* __restrict__ Sb,
                                                 float* __restrict__ s,
                                                 float* __restrict__ gwT) {
  const int bid = blockIdx.x, tid = threadIdx.x;
  if (bid < (B_ * C_ * C_) / 256) {
    size_t idx = (size_t)bid * 256 + tid;
    float acc = 0.f;
    for (int sp = 0; sp < SPLITK; sp++) acc += Spart[(size_t)sp * B_ * C_ * C_ + idx];
    S[idx] = acc;
    Sb[idx] = f2bf(acc);
  } else if (bid < (B_ * C_ * C_) / 256 + (B_ * C_) / 256) {
    int idx2 = (bid - (B_ * C_ * C_) / 256) * 256 + tid;
    float acc = 0.f;
#pragma unroll 8
    for (int i = 0; i < 64; i++) acc += spartial[(size_t)i * (B_ * C_) + idx2];
    s[idx2] = acc;
  } else {
    int t = bid - ((B_ * C_ * C_) / 256 + (B_ * C_) / 256);
    int o = t * 8 + (tid & 7);
    int cbase = (tid >> 3) * 8;
#pragma unroll
    for (int k = 0; k < 8; k++) {
      int c = cbase + k;
      gwT[c * OC_ + o] = g_w[o * C_ + c];
    }
  }
}

// MT[b][o][op] for a 4-op tile. grid: B*32 = 256 blocks, 256 thr.
__global__ __launch_bounds__(256) void k_mid1(const float* __restrict__ S,
                                              const float* __restrict__ s,
                                              const float* __restrict__ phi_w,
                                              const float* __restrict__ phi_b,
                                              const float* __restrict__ gwT,
                                              const float* __restrict__ g_b,
                                              float* __restrict__ MT) {
  const int b = blockIdx.x >> 5, ot = blockIdx.x & 31;
  const int tid = threadIdx.x;
  __shared__ float pw[4][257], t2[4][257], sl[256], ps_s[4], pb_s[4], redw[4][4];
  sl[tid] = s[b * C_ + tid];
#pragma unroll
  for (int r = 0; r < 4; r++) pw[r][tid] = phi_w[(ot * 4 + r) * C_ + tid];
  if (tid < 4) pb_s[tid] = phi_b[ot * 4 + tid];
  __syncthreads();
  float acc4[4] = {};
  const float* Sbr = S + (size_t)b * C_ * C_;
#pragma unroll 4
  for (int cp = 0; cp < C_; cp++) {
    float sv = Sbr[(size_t)cp * C_ + tid];
#pragma unroll
    for (int r = 0; r < 4; r++) acc4[r] += pw[r][cp] * sv;
  }
  const int lane = tid & 63, w = tid >> 6;
#pragma unroll
  for (int r = 0; r < 4; r++) {
    float v = pw[r][tid] * sl[tid];
#pragma unroll
    for (int off = 1; off < 64; off <<= 1) v += __shfl_xor(v, off, 64);
    if (lane == 0) redw[w][r] = v;
  }
#pragma unroll
  for (int r = 0; r < 4; r++) t2[r][tid] = acc4[r] + pb_s[r] * sl[tid];
  __syncthreads();
  if (tid < 4) ps_s[tid] = redw[0][tid] + redw[1][tid] + redw[2][tid] + redw[3][tid];
  __syncthreads();
  const int o = tid & 127, half = tid >> 7;
  float m0 = 0.f, m1 = 0.f;
#pragma unroll 4
  for (int c = 0; c < C_; c++) {
    float gv = gwT[c * OC_ + o];
    m0 += t2[half * 2][c] * gv;
    m1 += t2[half * 2 + 1][c] * gv;
  }
  float gb = g_b[o];
  int r0 = half * 2;
  MT[((size_t)b * OC_ + o) * OC_ + ot * 4 + r0]     = m0 + (ps_s[r0] + (float)L_ * pb_s[r0]) * gb;
  MT[((size_t)b * OC_ + o) * OC_ + ot * 4 + r0 + 1] = m1 + (ps_s[r0 + 1] + (float)L_ * pb_s[r0 + 1]) * gb;
}

// U -> q -> Qb(bf16) -> qs,sum1 for a 4-c-row tile. grid: B*64 = 512 blocks, 256 thr.
__global__ __launch_bounds__(256) void k_mid2(const float* __restrict__ MT,
                                              const float* __restrict__ W_w,
                                              const float* __restrict__ theta_w,
                                              const float* __restrict__ theta_b,
                                              const float* __restrict__ W_b,
                                              const float* __restrict__ s,
                                              u16* __restrict__ Qb,
                                              float* __restrict__ qv,
                                              float* __restrict__ qs_g,
                                              float* __restrict__ sum1) {
  const int b = blockIdx.x >> 6, ct = blockIdx.x & 63;
  const int c0 = ct * 4;
  const int tid = threadIdx.x;
  __shared__ float ww[4][OC_], u_s[4][OC_ + 2], s_l[C_], q_s[4], redq[4][4];
  s_l[tid] = s[b * C_ + tid];
#pragma unroll
  for (int i = tid; i < 4 * OC_; i += 256)
    ww[i >> 7][i & 127] = W_w[(c0 + (i >> 7)) * OC_ + (i & 127)];
  __syncthreads();
  const int op = tid & 127, rh = tid >> 7;
  float ua0 = 0.f, ua1 = 0.f;
  const float* MTb = MT + (size_t)b * OC_ * OC_;
#pragma unroll 4
  for (int o = 0; o < OC_; o++) {
    float mv = MTb[(size_t)o * OC_ + op];
    ua0 += ww[rh * 2][o] * mv;
    ua1 += ww[rh * 2 + 1][o] * mv;
  }
  u_s[rh * 2][op] = ua0 * (1.f / (float)L_);
  u_s[rh * 2 + 1][op] = ua1 * (1.f / (float)L_);
  __syncthreads();
  {
    const int r = tid >> 6, lane = tid & 63;
    float v = u_s[r][lane] * theta_b[lane] + u_s[r][lane + 64] * theta_b[lane + 64];
#pragma unroll
    for (int off = 1; off < 64; off <<= 1) v += __shfl_xor(v, off, 64);
    if (lane == 0) {
      float qval = v + W_b[c0 + r];
      q_s[r] = qval;
      qv[b * C_ + c0 + r] = qval;
    }
  }
  float qa[4] = {};
#pragma unroll 2
  for (int o = 0; o < OC_; o++) {
    float tv = theta_w[(size_t)o * C_ + tid];
#pragma unroll
    for (int r = 0; r < 4; r++) qa[r] += u_s[r][o] * tv;
  }
#pragma unroll
  for (int r = 0; r < 4; r++)
    Qb[((size_t)b * C_ + c0 + r) * C_ + tid] = f2bf(qa[r]);
  const int lane = tid & 63, w = tid >> 6;
#pragma unroll
  for (int r = 0; r < 4; r++) {
    float v = qa[r] * s_l[tid];
#pragma unroll
    for (int off = 1; off < 64; off <<= 1) v += __shfl_xor(v, off, 64);
    if (lane == 0) redq[w][r] = v;
  }
  __syncthreads();
  if (tid < 4) {
    float qs = redq[0][tid] + redq[1][tid] + redq[2][tid] + redq[3][tid];
    qs_g[b * C_ + c0 + tid] = qs;
    sum1[b * C_ + c0 + tid] = qs + (float)L_ * q_s[tid];
  }
}

// e2 partials via MFMA, k-split x4. grid: (4 ks, 4 (chs*2+ct), B) = 128 blocks.
__global__ __launch_bounds__(256) void k_ystat(const u16* __restrict__ Qb,
                                               const u16* __restrict__ Sb,
                                               float* __restrict__ e2part) {
  const int b = blockIdx.z;
  const int chs = blockIdx.y >> 1, ct = blockIdx.y & 1;
  const int ks = blockIdx.x;
  __shared__ u16 lds[2 * 128 * 64];
  __shared__ float e2s[128][2];
  const int tid = threadIdx.x, lane = tid & 63;
  const int wid = tid >> 6, wr = wid >> 1, wc = wid & 1;
  const u16* Abase = Qb + ((size_t)b * C_ + ct * 128) * C_;
  const u16* Bbase = Sb + ((size_t)b * C_ + chs * 128) * C_;
  const int k0 = ks * 64;
  f32x4 acc[4][4] = {};
#pragma unroll
  for (int ch = 0; ch < 4; ch++) {
    int d = ch * 4096 + tid * 16;
    int row = d >> 7;
    int kb = (d & 127) ^ ((row & 7) << 4);
    gload_lds16(Abase + (size_t)row * C_ + k0 + (kb >> 1), (char*)lds + d);
    gload_lds16(Bbase + (size_t)row * C_ + k0 + (kb >> 1), (char*)lds + 16384 + d);
  }
  asm volatile("s_waitcnt vmcnt(0)" ::: "memory");
  __syncthreads();
#pragma unroll
  for (int kk = 0; kk < 2; kk++) {
    bf16x8 af[4], bfr[4];
#pragma unroll
    for (int m = 0; m < 4; m++) {
      int row = wr * 64 + m * 16 + (lane & 15);
      int kb = ((kk << 6) + ((lane >> 4) << 4)) ^ ((row & 7) << 4);
      af[m] = *(const bf16x8*)((const char*)lds + row * 128 + kb);
    }
#pragma unroll
    for (int n = 0; n < 4; n++) {
      int row = wc * 64 + n * 16 + (lane & 15);
      int kb = ((kk << 6) + ((lane >> 4) << 4)) ^ ((row & 7) << 4);
      bfr[n] = *(const bf16x8*)((const char*)lds + 16384 + row * 128 + kb);
    }
#pragma unroll
    for (int m = 0; m < 4; m++)
#pragma unroll
      for (int n = 0; n < 4; n++)
        acc[m][n] = __builtin_amdgcn_mfma_f32_16x16x32_bf16(af[m], bfr[n], acc[m][n], 0, 0, 0);
  }
  float e2a[4][4];
#pragma unroll
  for (int m = 0; m < 4; m++)
#pragma unroll
    for (int r = 0; r < 4; r++) e2a[m][r] = 0.f;
#pragma unroll
  for (int m = 0; m < 4; m++)
#pragma unroll
    for (int n = 0; n < 4; n++) {
      int ch = chs * 128 + wc * 64 + n * 16 + (lane & 15);
#pragma unroll
      for (int r = 0; r < 4; r++) {
        int c_loc = wr * 64 + m * 16 + ((lane >> 4) << 2) + r;
        float q2 = bf2f(Qb[((size_t)b * C_ + ct * 128 + c_loc) * C_ + ch]);
        e2a[m][r] += acc[m][n][r] * q2;
      }
    }
#pragma unroll
  for (int m = 0; m < 4; m++)
#pragma unroll
    for (int r = 0; r < 4; r++) {
      float v = e2a[m][r];
      v += __shfl_xor(v, 1, 64);
      v += __shfl_xor(v, 2, 64);
      v += __shfl_xor(v, 4, 64);
      v += __shfl_xor(v, 8, 64);
      if ((lane & 15) == 0) {
        int c_loc = wr * 64 + m * 16 + ((lane >> 4) << 2) + r;
        e2s[c_loc][wc] = v;
      }
    }
  __syncthreads();
  if (tid < 128)
    e2part[(((size_t)chs * 4 + ks) * B_ + b) * C_ + ct * 128 + tid] =
        e2s[tid][0] + e2s[tid][1];
}

// BN finalize + build Qs = bf16(gsc*Q) + I, qp. grid: B*16 = 128 blocks, 256 thr.
__global__ __launch_bounds__(256) void k_build(const u16* __restrict__ Qb,
                                               const float* __restrict__ qv,
                                               const float* __restrict__ qs_g,
                                               const float* __restrict__ sum1,
                                               const float* __restrict__ e2part,
                                               const float* __restrict__ gamma,
                                               const float* __restrict__ beta,
                                               u16* __restrict__ Qs,
                                               float* __restrict__ qp_g) {
  const int b = blockIdx.x >> 4, rq = blockIdx.x & 15;
  const int tid = threadIdx.x;
  __shared__ float gsc_s[16];
  if (tid < 16) {
    int c = rq * 16 + tid;
    float m = 0.f, e = 0.f;
#pragma unroll
    for (int bb = 0; bb < B_; bb++) {
      m += sum1[bb * C_ + c];
      float e2 = 0.f;
#pragma unroll
      for (int sl = 0; sl < 8; sl++) e2 += e2part[((size_t)sl * B_ + bb) * C_ + c];
      float qq = qv[bb * C_ + c], qs = qs_g[bb * C_ + c];
      e += e2 + 2.f * qq * qs + (float)L_ * qq * qq;
    }
    const float inv_n = 1.f / (float)(B_ * L_);
    m *= inv_n;
    e *= inv_n;
    float var = e - m * m;
    float g = gamma[c] * rsqrtf(var + EPS_);
    gsc_s[tid] = g;
    qp_g[b * C_ + c] = g * (qv[b * C_ + c] - m) + beta[c];
  }
  __syncthreads();
  const int row = tid >> 4;            // 16 rows
  const int c = rq * 16 + row;
  const int seg = (tid & 15) * 16;     // 16 cols per thread
  const float g = gsc_s[row];
  const u16x8* src = (const u16x8*)(Qb + ((size_t)b * C_ + c) * C_ + seg);
  u16x8 v0 = src[0], v1 = src[1];
  u16x8 o0, o1;
#pragma unroll
  for (int j = 0; j < 8; j++) {
    float a = g * bf2f(v0[j]);
    if (seg + j == c) a += 1.f;
    o0[j] = f2bf(a);
  }
#pragma unroll
  for (int j = 0; j < 8; j++) {
    float a = g * bf2f(v1[j]);
    if (seg + 8 + j == c) a += 1.f;
    o1[j] = f2bf(a);
  }
  u16x8* dst = (u16x8*)(Qs + ((size_t)b * C_ + c) * C_ + seg);
  dst[0] = o0;
  dst[1] = o1;
}

// out[b] = Qs[b] @ Xb[b] + qp.  LDS-free direct-load GEMM.
// grid: (L/128, C/128, B) = 512 blocks, 256 thr.
__global__ __launch_bounds__(256) void k_out(const u16* __restrict__ Qs,
                                             const float* __restrict__ qp_g,
                                             const u16* __restrict__ XbT,
                                             float* __restrict__ out) {
  const int b = blockIdx.z, ct = blockIdx.y, lt = blockIdx.x;
  const int tid = threadIdx.x, lane = tid & 63;
  const int wid = tid >> 6, wr = wid >> 1, wc = wid & 1;
  const u16* Ab = Qs + ((size_t)b * C_ + ct * 128) * C_;
  const u16* Bb = XbT + ((size_t)b * L_ + lt * 128) * C_;
  const int khalf = (lane >> 4) << 3;
  f32x4 acc[4][4] = {};
#pragma unroll 2
  for (int k0 = 0; k0 < C_; k0 += 32) {
    bf16x8 af[4], bfr[4];
#pragma unroll
    for (int m = 0; m < 4; m++)
      af[m] = *(const bf16x8*)(Ab + (size_t)(wr * 64 + m * 16 + (lane & 15)) * C_ + k0 + khalf);
#pragma unroll
    for (int n = 0; n < 4; n++)
      bfr[n] = *(const bf16x8*)(Bb + (size_t)(wc * 64 + n * 16 + (lane & 15)) * C_ + k0 + khalf);
#pragma unroll
    for (int m = 0; m < 4; m++)
#pragma unroll
      for (int n = 0; n < 4; n++)
        acc[m][n] = __builtin_amdgcn_mfma_f32_16x16x32_bf16(af[m], bfr[n], acc[m][n], 0, 0, 0);
  }
  float qpr[4][4];
#pragma unroll
  for (int m = 0; m < 4; m++)
#pragma unroll
    for (int r = 0; r < 4; r++)
      qpr[m][r] = qp_g[b * C_ + ct * 128 + wr * 64 + m * 16 + ((lane >> 4) << 2) + r];
#pragma unroll
  for (int m = 0; m < 4; m++)
#pragma unroll
    for (int n = 0; n < 4; n++) {
      int c = ct * 128 + wr * 64 + m * 16 + ((lane >> 4) << 2);
      int l = lt * 128 + wc * 64 + n * 16 + (lane & 15);
#pragma unroll
      for (int r = 0; r < 4; r++) {
        size_t gi = ((size_t)b * C_ + c + r) * L_ + l;
        out[gi] = acc[m][n][r] + qpr[m][r];
      }
    }
}

extern "C" void kernel_launch(void* const* d_in, const int* in_sizes, int n_in,
                              void* d_out, int out_size, void* d_ws, size_t ws_size,
                              hipStream_t stream) {
  const float* x       = (const float*)d_in[0];
  const float* g_w     = (const float*)d_in[1];
  const float* g_b     = (const float*)d_in[2];
  const float* theta_w = (const float*)d_in[3];
  const float* theta_b = (const float*)d_in[4];
  const float* phi_w   = (const float*)d_in[5];
  const float* phi_b   = (const float*)d_in[6];
  const float* W_w     = (const float*)d_in[7];
  const float* W_b     = (const float*)d_in[8];
  const float* gamma   = (const float*)d_in[9];
  const float* beta    = (const float*)d_in[10];
  float* out = (float*)d_out;

  float* ws = (float*)d_ws;
  size_t off = 0;
  float* Spart    = ws + off; off += (size_t)SPLITK * B_ * C_ * C_;
  float* S        = ws + off; off += (size_t)B_ * C_ * C_;
  float* spartial = ws + off; off += (size_t)B_ * C_ * 64;
  float* s_       = ws + off; off += B_ * C_;
  float* gwT      = ws + off; off += C_ * OC_;
  float* MT       = ws + off; off += (size_t)B_ * OC_ * OC_;
  float* qv       = ws + off; off += B_ * C_;
  float* qs_g     = ws + off; off += B_ * C_;
  float* sum1     = ws + off; off += B_ * C_;
  float* e2part   = ws + off; off += 8 * B_ * C_;
  float* qp_g     = ws + off; off += B_ * C_;
  u16* Sb  = (u16*)(ws + off); off += (size_t)B_ * C_ * C_ / 2;
  u16* Qb  = (u16*)(ws + off); off += (size_t)B_ * C_ * C_ / 2;
  u16* Qs  = (u16*)(ws + off); off += (size_t)B_ * C_ * C_ / 2;
  u16* Xb  = (u16*)(ws + off); off += (size_t)B_ * C_ * L_ / 2;
  u16* XbT = (u16*)(ws + off); off += (size_t)B_ * C_ * L_ / 2;

  k_cvt<<<dim3(L_ / 64, C_ / 64, B_), 256, 0, stream>>>(x, Xb, XbT, spartial);
  k_xxt<<<dim3(16, SPLITK, B_), 256, 0, stream>>>(Xb, Spart);
  k_sreduce<<<(B_ * C_ * C_) / 256 + (B_ * C_) / 256 + 16, 256, 0, stream>>>(
      Spart, spartial, g_w, S, Sb, s_, gwT);
  k_mid1<<<B_ * 32, 256, 0, stream>>>(S, s_, phi_w, phi_b, gwT, g_b, MT);
  k_mid2<<<B_ * 64, 256, 0, stream>>>(MT, W_w, theta_w, theta_b, W_b, s_,
                                      Qb, qv, qs_g, sum1);
  k_ystat<<<dim3(4, 4, B_), 256, 0, stream>>>(Qb, Sb, e2part);
  k_build<<<B_ * 16, 256, 0, stream>>>(Qb, qv, qs_g, sum1, e2part, gamma, beta,
                                       Qs, qp_g);
  k_out<<<dim3(L_ / 128, C_ / 128, B_), 256, 0, stream>>>(Qs, qp_g, XbT, out);
}

// Round 9
// 120.331 us; speedup vs baseline: 1.1113x; 1.1113x over previous
//
#include <hip/hip_runtime.h>
#include <hip/hip_bf16.h>

#define B_ 8
#define C_ 256
#define OC_ 128
#define L_ 4096
#define EPS_ 1e-5f
#define SPLITK 4

typedef unsigned short u16;
typedef __attribute__((ext_vector_type(4))) unsigned short u16x4;
typedef __attribute__((ext_vector_type(8))) unsigned short u16x8;
typedef __attribute__((ext_vector_type(4))) float f32x4;
typedef __attribute__((ext_vector_type(8))) short bf16x8;

__device__ inline u16 f2bf(float f) {
  union { __hip_bfloat16 h; u16 u; } v;
  v.h = __float2bfloat16(f);
  return v.u;
}
__device__ inline float bf2f(u16 u) {
  union { float f; unsigned u; } v;
  v.u = ((unsigned)u) << 16;
  return v.f;
}

__device__ inline void gload_lds16(const void* g, void* lds) {
  __builtin_amdgcn_global_load_lds(
      (const __attribute__((address_space(1))) unsigned int*)g,
      (__attribute__((address_space(3))) unsigned int*)lds, 16, 0, 0);
}

// x -> Xb[b][c][l], XbT[b][l][c] (bf16), + partial row sums spartial[ltile][b*C+c]
__global__ __launch_bounds__(256) void k_cvt(const float* __restrict__ x,
                                             u16* __restrict__ Xb,
                                             u16* __restrict__ XbT,
                                             float* __restrict__ spartial) {
  __shared__ u16 T[64][73];
  __shared__ float P[64][17];
  const int b = blockIdx.z, c0 = blockIdx.y * 64, l0 = blockIdx.x * 64;
  const int tid = threadIdx.x;
#pragma unroll
  for (int it = 0; it < 4; ++it) {
    int idx = it * 256 + tid;
    int row = idx >> 4;
    int col = (idx & 15) << 2;
    size_t gi = ((size_t)(b * C_ + c0 + row)) * L_ + l0 + col;
    float4 v = *(const float4*)(x + gi);
    u16 u0 = f2bf(v.x), u1 = f2bf(v.y), u2 = f2bf(v.z), u3 = f2bf(v.w);
    u16x4 u = {u0, u1, u2, u3};
    *(u16x4*)(Xb + gi) = u;
    T[row][col] = u0; T[row][col + 1] = u1; T[row][col + 2] = u2; T[row][col + 3] = u3;
    P[row][idx & 15] = v.x + v.y + v.z + v.w;
  }
  __syncthreads();
  if (tid < 64) {
    float acc = 0.f;
#pragma unroll
    for (int j = 0; j < 16; j++) acc += P[tid][j];
    spartial[(size_t)blockIdx.x * (B_ * C_) + b * C_ + c0 + tid] = acc;
  }
#pragma unroll
  for (int it = 0; it < 4; ++it) {
    int idx = it * 256 + tid;
    int lrow = idx >> 4;
    int ccol = (idx & 15) << 2;
    u16x4 u = {T[ccol][lrow], T[ccol + 1][lrow], T[ccol + 2][lrow], T[ccol + 3][lrow]};
    *(u16x4*)(XbT + ((size_t)b * L_ + l0 + lrow) * C_ + c0 + ccol) = u;
  }
}

// S[b] = Xb Xb^T via MFMA bf16, split-K, 64x64 tiles, 2-phase dbuf.
// grid: (16, SPLITK, B) = 512 blocks, 256 thr.
__global__ __launch_bounds__(256) void k_xxt(const u16* __restrict__ Xb,
                                             float* __restrict__ Spart) {
  const int b = blockIdx.z, split = blockIdx.y;
  const int ti = blockIdx.x >> 2, tj = blockIdx.x & 3;
  __shared__ u16 lds[2][2][64 * 64];
  const int tid = threadIdx.x, lane = tid & 63;
  const int wid = tid >> 6, wr = wid >> 1, wc = wid & 1;
  const u16* Arows = Xb + ((size_t)b * C_ + ti * 64) * L_;
  const u16* Brows = Xb + ((size_t)b * C_ + tj * 64) * L_;
  const int k0 = split * (L_ / SPLITK);
  f32x4 acc[2][2] = {};

  auto STAGE = [&](int buf, int kt) {
#pragma unroll
    for (int ch = 0; ch < 2; ch++) {
      int d = ch * 4096 + tid * 16;
      int row = d >> 7;
      int kb = (d & 127) ^ ((row & 7) << 4);
      gload_lds16(Arows + (size_t)row * L_ + k0 + kt + (kb >> 1), (char*)lds[buf][0] + d);
      gload_lds16(Brows + (size_t)row * L_ + k0 + kt + (kb >> 1), (char*)lds[buf][1] + d);
    }
  };

  STAGE(0, 0);
  asm volatile("s_waitcnt vmcnt(0)" ::: "memory");
  __syncthreads();
  int cur = 0;
  for (int kt = 0; kt < L_ / SPLITK; kt += 64) {
    if (kt + 64 < L_ / SPLITK) STAGE(cur ^ 1, kt + 64);
#pragma unroll
    for (int kk = 0; kk < 2; kk++) {
      bf16x8 af[2], bfr[2];
#pragma unroll
      for (int m = 0; m < 2; m++) {
        int row = wr * 32 + m * 16 + (lane & 15);
        int kb = ((kk << 6) + ((lane >> 4) << 4)) ^ ((row & 7) << 4);
        af[m] = *(const bf16x8*)((const char*)lds[cur][0] + row * 128 + kb);
      }
#pragma unroll
      for (int n = 0; n < 2; n++) {
        int row = wc * 32 + n * 16 + (lane & 15);
        int kb = ((kk << 6) + ((lane >> 4) << 4)) ^ ((row & 7) << 4);
        bfr[n] = *(const bf16x8*)((const char*)lds[cur][1] + row * 128 + kb);
      }
#pragma unroll
      for (int m = 0; m < 2; m++)
#pragma unroll
        for (int n = 0; n < 2; n++)
          acc[m][n] = __builtin_amdgcn_mfma_f32_16x16x32_bf16(af[m], bfr[n], acc[m][n], 0, 0, 0);
    }
    asm volatile("s_waitcnt vmcnt(0)" ::: "memory");
    __syncthreads();
    cur ^= 1;
  }
  float* Sp = Spart + ((size_t)split * B_ + b) * C_ * C_;
#pragma unroll
  for (int m = 0; m < 2; m++)
#pragma unroll
    for (int n = 0; n < 2; n++) {
      int r0 = ti * 64 + wr * 32 + m * 16 + ((lane >> 4) << 2);
      int c0 = tj * 64 + wc * 32 + n * 16 + (lane & 15);
#pragma unroll
      for (int r = 0; r < 4; r++)
        Sp[(size_t)(r0 + r) * C_ + c0] = acc[m][n][r];
    }
}

// blocks <2048: S (+ Sb bf16); 2048-2055: s; 2056-2071: gwT = g_w^T
__global__ __launch_bounds__(256) void k_sreduce(const float* __restrict__ Spart,
                                                 const float* __restrict__ spartial,
                                                 const float* __restrict__ g_w,
                                                 float* __restrict__ S,
                                                 u16* __restrict__ Sb,
                                                 float* __restrict__ s,
                                                 float* __restrict__ gwT) {
  const int bid = blockIdx.x, tid = threadIdx.x;
  if (bid < (B_ * C_ * C_) / 256) {
    size_t idx = (size_t)bid * 256 + tid;
    float acc = 0.f;
    for (int sp = 0; sp < SPLITK; sp++) acc += Spart[(size_t)sp * B_ * C_ * C_ + idx];
    S[idx] = acc;
    Sb[idx] = f2bf(acc);
  } else if (bid < (B_ * C_ * C_) / 256 + (B_ * C_) / 256) {
    int idx2 = (bid - (B_ * C_ * C_) / 256) * 256 + tid;
    float acc = 0.f;
#pragma unroll 8
    for (int i = 0; i < 64; i++) acc += spartial[(size_t)i * (B_ * C_) + idx2];
    s[idx2] = acc;
  } else {
    int t = bid - ((B_ * C_ * C_) / 256 + (B_ * C_) / 256);
    int o = t * 8 + (tid & 7);
    int cbase = (tid >> 3) * 8;
#pragma unroll
    for (int k = 0; k < 8; k++) {
      int c = cbase + k;
      gwT[c * OC_ + o] = g_w[o * C_ + c];
    }
  }
}

// MT[b][o][op] for a 4-op tile. grid: B*32 = 256 blocks, 256 thr.
__global__ __launch_bounds__(256) void k_mid1(const float* __restrict__ S,
                                              const float* __restrict__ s,
                                              const float* __restrict__ phi_w,
                                              const float* __restrict__ phi_b,
                                              const float* __restrict__ gwT,
                                              const float* __restrict__ g_b,
                                              float* __restrict__ MT) {
  const int b = blockIdx.x >> 5, ot = blockIdx.x & 31;
  const int tid = threadIdx.x;
  __shared__ float pw[4][257], t2[4][257], sl[256], ps_s[4], pb_s[4], redw[4][4];
  sl[tid] = s[b * C_ + tid];
#pragma unroll
  for (int r = 0; r < 4; r++) pw[r][tid] = phi_w[(ot * 4 + r) * C_ + tid];
  if (tid < 4) pb_s[tid] = phi_b[ot * 4 + tid];
  __syncthreads();
  float acc4[4] = {};
  const float* Sbr = S + (size_t)b * C_ * C_;
#pragma unroll 4
  for (int cp = 0; cp < C_; cp++) {
    float sv = Sbr[(size_t)cp * C_ + tid];
#pragma unroll
    for (int r = 0; r < 4; r++) acc4[r] += pw[r][cp] * sv;
  }
  const int lane = tid & 63, w = tid >> 6;
#pragma unroll
  for (int r = 0; r < 4; r++) {
    float v = pw[r][tid] * sl[tid];
#pragma unroll
    for (int off = 1; off < 64; off <<= 1) v += __shfl_xor(v, off, 64);
    if (lane == 0) redw[w][r] = v;
  }
#pragma unroll
  for (int r = 0; r < 4; r++) t2[r][tid] = acc4[r] + pb_s[r] * sl[tid];
  __syncthreads();
  if (tid < 4) ps_s[tid] = redw[0][tid] + redw[1][tid] + redw[2][tid] + redw[3][tid];
  __syncthreads();
  const int o = tid & 127, half = tid >> 7;
  float m0 = 0.f, m1 = 0.f;
#pragma unroll 4
  for (int c = 0; c < C_; c++) {
    float gv = gwT[c * OC_ + o];
    m0 += t2[half * 2][c] * gv;
    m1 += t2[half * 2 + 1][c] * gv;
  }
  float gb = g_b[o];
  int r0 = half * 2;
  MT[((size_t)b * OC_ + o) * OC_ + ot * 4 + r0]     = m0 + (ps_s[r0] + (float)L_ * pb_s[r0]) * gb;
  MT[((size_t)b * OC_ + o) * OC_ + ot * 4 + r0 + 1] = m1 + (ps_s[r0 + 1] + (float)L_ * pb_s[r0 + 1]) * gb;
}

// U -> q -> Qb(bf16) -> qs,sum1 for a 4-c-row tile. grid: B*64 = 512 blocks, 256 thr.
__global__ __launch_bounds__(256) void k_mid2(const float* __restrict__ MT,
                                              const float* __restrict__ W_w,
                                              const float* __restrict__ theta_w,
                                              const float* __restrict__ theta_b,
                                              const float* __restrict__ W_b,
                                              const float* __restrict__ s,
                                              u16* __restrict__ Qb,
                                              float* __restrict__ qv,
                                              float* __restrict__ qs_g,
                                              float* __restrict__ sum1) {
  const int b = blockIdx.x >> 6, ct = blockIdx.x & 63;
  const int c0 = ct * 4;
  const int tid = threadIdx.x;
  __shared__ float ww[4][OC_], u_s[4][OC_ + 2], s_l[C_], q_s[4], redq[4][4];
  s_l[tid] = s[b * C_ + tid];
#pragma unroll
  for (int i = tid; i < 4 * OC_; i += 256)
    ww[i >> 7][i & 127] = W_w[(c0 + (i >> 7)) * OC_ + (i & 127)];
  __syncthreads();
  const int op = tid & 127, rh = tid >> 7;
  float ua0 = 0.f, ua1 = 0.f;
  const float* MTb = MT + (size_t)b * OC_ * OC_;
#pragma unroll 4
  for (int o = 0; o < OC_; o++) {
    float mv = MTb[(size_t)o * OC_ + op];
    ua0 += ww[rh * 2][o] * mv;
    ua1 += ww[rh * 2 + 1][o] * mv;
  }
  u_s[rh * 2][op] = ua0 * (1.f / (float)L_);
  u_s[rh * 2 + 1][op] = ua1 * (1.f / (float)L_);
  __syncthreads();
  {
    const int r = tid >> 6, lane = tid & 63;
    float v = u_s[r][lane] * theta_b[lane] + u_s[r][lane + 64] * theta_b[lane + 64];
#pragma unroll
    for (int off = 1; off < 64; off <<= 1) v += __shfl_xor(v, off, 64);
    if (lane == 0) {
      float qval = v + W_b[c0 + r];
      q_s[r] = qval;
      qv[b * C_ + c0 + r] = qval;
    }
  }
  float qa[4] = {};
#pragma unroll 2
  for (int o = 0; o < OC_; o++) {
    float tv = theta_w[(size_t)o * C_ + tid];
#pragma unroll
    for (int r = 0; r < 4; r++) qa[r] += u_s[r][o] * tv;
  }
#pragma unroll
  for (int r = 0; r < 4; r++)
    Qb[((size_t)b * C_ + c0 + r) * C_ + tid] = f2bf(qa[r]);
  const int lane = tid & 63, w = tid >> 6;
#pragma unroll
  for (int r = 0; r < 4; r++) {
    float v = qa[r] * s_l[tid];
#pragma unroll
    for (int off = 1; off < 64; off <<= 1) v += __shfl_xor(v, off, 64);
    if (lane == 0) redq[w][r] = v;
  }
  __syncthreads();
  if (tid < 4) {
    float qs = redq[0][tid] + redq[1][tid] + redq[2][tid] + redq[3][tid];
    qs_g[b * C_ + c0 + tid] = qs;
    sum1[b * C_ + c0 + tid] = qs + (float)L_ * q_s[tid];
  }
}

// e2 partials via MFMA, k-split x4. grid: (4 ks, 4 (chs*2+ct), B) = 128 blocks.
__global__ __launch_bounds__(256) void k_ystat(const u16* __restrict__ Qb,
                                               const u16* __restrict__ Sb,
                                               float* __restrict__ e2part) {
  const int b = blockIdx.z;
  const int chs = blockIdx.y >> 1, ct = blockIdx.y & 1;
  const int ks = blockIdx.x;
  __shared__ u16 lds[2 * 128 * 64];
  __shared__ float e2s[128][2];
  const int tid = threadIdx.x, lane = tid & 63;
  const int wid = tid >> 6, wr = wid >> 1, wc = wid & 1;
  const u16* Abase = Qb + ((size_t)b * C_ + ct * 128) * C_;
  const u16* Bbase = Sb + ((size_t)b * C_ + chs * 128) * C_;
  const int k0 = ks * 64;
  f32x4 acc[4][4] = {};
#pragma unroll
  for (int ch = 0; ch < 4; ch++) {
    int d = ch * 4096 + tid * 16;
    int row = d >> 7;
    int kb = (d & 127) ^ ((row & 7) << 4);
    gload_lds16(Abase + (size_t)row * C_ + k0 + (kb >> 1), (char*)lds + d);
    gload_lds16(Bbase + (size_t)row * C_ + k0 + (kb >> 1), (char*)lds + 16384 + d);
  }
  asm volatile("s_waitcnt vmcnt(0)" ::: "memory");
  __syncthreads();
#pragma unroll
  for (int kk = 0; kk < 2; kk++) {
    bf16x8 af[4], bfr[4];
#pragma unroll
    for (int m = 0; m < 4; m++) {
      int row = wr * 64 + m * 16 + (lane & 15);
      int kb = ((kk << 6) + ((lane >> 4) << 4)) ^ ((row & 7) << 4);
      af[m] = *(const bf16x8*)((const char*)lds + row * 128 + kb);
    }
#pragma unroll
    for (int n = 0; n < 4; n++) {
      int row = wc * 64 + n * 16 + (lane & 15);
      int kb = ((kk << 6) + ((lane >> 4) << 4)) ^ ((row & 7) << 4);
      bfr[n] = *(const bf16x8*)((const char*)lds + 16384 + row * 128 + kb);
    }
#pragma unroll
    for (int m = 0; m < 4; m++)
#pragma unroll
      for (int n = 0; n < 4; n++)
        acc[m][n] = __builtin_amdgcn_mfma_f32_16x16x32_bf16(af[m], bfr[n], acc[m][n], 0, 0, 0);
  }
  float e2a[4][4];
#pragma unroll
  for (int m = 0; m < 4; m++)
#pragma unroll
    for (int r = 0; r < 4; r++) e2a[m][r] = 0.f;
#pragma unroll
  for (int m = 0; m < 4; m++)
#pragma unroll
    for (int n = 0; n < 4; n++) {
      int ch = chs * 128 + wc * 64 + n * 16 + (lane & 15);
#pragma unroll
      for (int r = 0; r < 4; r++) {
        int c_loc = wr * 64 + m * 16 + ((lane >> 4) << 2) + r;
        float q2 = bf2f(Qb[((size_t)b * C_ + ct * 128 + c_loc) * C_ + ch]);
        e2a[m][r] += acc[m][n][r] * q2;
      }
    }
#pragma unroll
  for (int m = 0; m < 4; m++)
#pragma unroll
    for (int r = 0; r < 4; r++) {
      float v = e2a[m][r];
      v += __shfl_xor(v, 1, 64);
      v += __shfl_xor(v, 2, 64);
      v += __shfl_xor(v, 4, 64);
      v += __shfl_xor(v, 8, 64);
      if ((lane & 15) == 0) {
        int c_loc = wr * 64 + m * 16 + ((lane >> 4) << 2) + r;
        e2s[c_loc][wc] = v;
      }
    }
  __syncthreads();
  if (tid < 128)
    e2part[(((size_t)chs * 4 + ks) * B_ + b) * C_ + ct * 128 + tid] =
        e2s[tid][0] + e2s[tid][1];
}

// BN finalize + build Qs = bf16(gsc*Q) + I, qp. grid: B*16 = 128 blocks, 256 thr.
__global__ __launch_bounds__(256) void k_build(const u16* __restrict__ Qb,
                                               const float* __restrict__ qv,
                                               const float* __restrict__ qs_g,
                                               const float* __restrict__ sum1,
                                               const float* __restrict__ e2part,
                                               const float* __restrict__ gamma,
                                               const float* __restrict__ beta,
                                               u16* __restrict__ Qs,
                                               float* __restrict__ qp_g) {
  const int b = blockIdx.x >> 4, rq = blockIdx.x & 15;
  const int tid = threadIdx.x;
  __shared__ float gsc_s[16];
  if (tid < 16) {
    int c = rq * 16 + tid;
    float m = 0.f, e = 0.f;
#pragma unroll
    for (int bb = 0; bb < B_; bb++) {
      m += sum1[bb * C_ + c];
      float e2 = 0.f;
#pragma unroll
      for (int sl = 0; sl < 8; sl++) e2 += e2part[((size_t)sl * B_ + bb) * C_ + c];
      float qq = qv[bb * C_ + c], qs = qs_g[bb * C_ + c];
      e += e2 + 2.f * qq * qs + (float)L_ * qq * qq;
    }
    const float inv_n = 1.f / (float)(B_ * L_);
    m *= inv_n;
    e *= inv_n;
    float var = e - m * m;
    float g = gamma[c] * rsqrtf(var + EPS_);
    gsc_s[tid] = g;
    qp_g[b * C_ + c] = g * (qv[b * C_ + c] - m) + beta[c];
  }
  __syncthreads();
  const int row = tid >> 4;
  const int c = rq * 16 + row;
  const int seg = (tid & 15) * 16;
  const float g = gsc_s[row];
  const u16x8* src = (const u16x8*)(Qb + ((size_t)b * C_ + c) * C_ + seg);
  u16x8 v0 = src[0], v1 = src[1];
  u16x8 o0, o1;
#pragma unroll
  for (int j = 0; j < 8; j++) {
    float a = g * bf2f(v0[j]);
    if (seg + j == c) a += 1.f;
    o0[j] = f2bf(a);
  }
#pragma unroll
  for (int j = 0; j < 8; j++) {
    float a = g * bf2f(v1[j]);
    if (seg + 8 + j == c) a += 1.f;
    o1[j] = f2bf(a);
  }
  u16x8* dst = (u16x8*)(Qs + ((size_t)b * C_ + c) * C_ + seg);
  dst[0] = o0;
  dst[1] = o1;
}

// out[b] = Qs[b] @ Xb[b] + qp.  LDS 2-phase dbuf GEMM (residual folded into Qs).
// grid: (L/128, C/128, B) = 512 blocks, 256 thr.
__global__ __launch_bounds__(256) void k_out(const u16* __restrict__ Qs,
                                             const float* __restrict__ qp_g,
                                             const u16* __restrict__ XbT,
                                             float* __restrict__ out) {
  const int b = blockIdx.z, ct = blockIdx.y, lt = blockIdx.x;
  __shared__ u16 lds[2][2 * 128 * 64];
  __shared__ float qp_s[128];
  const int tid = threadIdx.x, lane = tid & 63;
  const int wid = tid >> 6, wr = wid >> 1, wc = wid & 1;
  if (tid < 128) qp_s[tid] = qp_g[b * C_ + ct * 128 + tid];
  const u16* Abase = Qs + ((size_t)b * C_ + ct * 128) * C_;
  const u16* Bbase = XbT + ((size_t)b * L_ + lt * 128) * C_;
  f32x4 acc[4][4] = {};
  auto STAGE = [&](int buf, int k0) {
#pragma unroll
    for (int ch = 0; ch < 4; ch++) {
      int d = ch * 4096 + tid * 16;
      int row = d >> 7;
      int kb = (d & 127) ^ ((row & 7) << 4);
      gload_lds16(Abase + (size_t)row * C_ + k0 + (kb >> 1), (char*)lds[buf] + d);
      gload_lds16(Bbase + (size_t)row * C_ + k0 + (kb >> 1), (char*)lds[buf] + 16384 + d);
    }
  };
  STAGE(0, 0);
  asm volatile("s_waitcnt vmcnt(0)" ::: "memory");
  __syncthreads();
  int cur = 0;
  for (int k0 = 0; k0 < C_; k0 += 64) {
    if (k0 + 64 < C_) STAGE(cur ^ 1, k0 + 64);
#pragma unroll
    for (int kk = 0; kk < 2; kk++) {
      bf16x8 af[4], bfr[4];
#pragma unroll
      for (int m = 0; m < 4; m++) {
        int row = wr * 64 + m * 16 + (lane & 15);
        int kb = ((kk << 6) + ((lane >> 4) << 4)) ^ ((row & 7) << 4);
        af[m] = *(const bf16x8*)((const char*)lds[cur] + row * 128 + kb);
      }
#pragma unroll
      for (int n = 0; n < 4; n++) {
        int row = wc * 64 + n * 16 + (lane & 15);
        int kb = ((kk << 6) + ((lane >> 4) << 4)) ^ ((row & 7) << 4);
        bfr[n] = *(const bf16x8*)((const char*)lds[cur] + 16384 + row * 128 + kb);
      }
#pragma unroll
      for (int m = 0; m < 4; m++)
#pragma unroll
        for (int n = 0; n < 4; n++)
          acc[m][n] = __builtin_amdgcn_mfma_f32_16x16x32_bf16(af[m], bfr[n], acc[m][n], 0, 0, 0);
    }
    asm volatile("s_waitcnt vmcnt(0)" ::: "memory");
    __syncthreads();
    cur ^= 1;
  }
#pragma unroll
  for (int m = 0; m < 4; m++)
#pragma unroll
    for (int n = 0; n < 4; n++) {
      int cl = wr * 64 + m * 16 + ((lane >> 4) << 2);
      int c = ct * 128 + cl;
      int l = lt * 128 + wc * 64 + n * 16 + (lane & 15);
#pragma unroll
      for (int r = 0; r < 4; r++) {
        size_t gi = ((size_t)b * C_ + c + r) * L_ + l;
        out[gi] = acc[m][n][r] + qp_s[cl + r];
      }
    }
}

extern "C" void kernel_launch(void* const* d_in, const int* in_sizes, int n_in,
                              void* d_out, int out_size, void* d_ws, size_t ws_size,
                              hipStream_t stream) {
  const float* x       = (const float*)d_in[0];
  const float* g_w     = (const float*)d_in[1];
  const float* g_b     = (const float*)d_in[2];
  const float* theta_w = (const float*)d_in[3];
  const float* theta_b = (const float*)d_in[4];
  const float* phi_w   = (const float*)d_in[5];
  const float* phi_b   = (const float*)d_in[6];
  const float* W_w     = (const float*)d_in[7];
  const float* W_b     = (const float*)d_in[8];
  const float* gamma   = (const float*)d_in[9];
  const float* beta    = (const float*)d_in[10];
  float* out = (float*)d_out;

  float* ws = (float*)d_ws;
  size_t off = 0;
  float* Spart    = ws + off; off += (size_t)SPLITK * B_ * C_ * C_;
  float* S        = ws + off; off += (size_t)B_ * C_ * C_;
  float* spartial = ws + off; off += (size_t)B_ * C_ * 64;
  float* s_       = ws + off; off += B_ * C_;
  float* gwT      = ws + off; off += C_ * OC_;
  float* MT       = ws + off; off += (size_t)B_ * OC_ * OC_;
  float* qv       = ws + off; off += B_ * C_;
  float* qs_g     = ws + off; off += B_ * C_;
  float* sum1     = ws + off; off += B_ * C_;
  float* e2part   = ws + off; off += 8 * B_ * C_;
  float* qp_g     = ws + off; off += B_ * C_;
  u16* Sb  = (u16*)(ws + off); off += (size_t)B_ * C_ * C_ / 2;
  u16* Qb  = (u16*)(ws + off); off += (size_t)B_ * C_ * C_ / 2;
  u16* Qs  = (u16*)(ws + off); off += (size_t)B_ * C_ * C_ / 2;
  u16* Xb  = (u16*)(ws + off); off += (size_t)B_ * C_ * L_ / 2;
  u16* XbT = (u16*)(ws + off); off += (size_t)B_ * C_ * L_ / 2;

  k_cvt<<<dim3(L_ / 64, C_ / 64, B_), 256, 0, stream>>>(x, Xb, XbT, spartial);
  k_xxt<<<dim3(16, SPLITK, B_), 256, 0, stream>>>(Xb, Spart);
  k_sreduce<<<(B_ * C_ * C_) / 256 + (B_ * C_) / 256 + 16, 256, 0, stream>>>(
      Spart, spartial, g_w, S, Sb, s_, gwT);
  k_mid1<<<B_ * 32, 256, 0, stream>>>(S, s_, phi_w, phi_b, gwT, g_b, MT);
  k_mid2<<<B_ * 64, 256, 0, stream>>>(MT, W_w, theta_w, theta_b, W_b, s_,
                                      Qb, qv, qs_g, sum1);
  k_ystat<<<dim3(4, 4, B_), 256, 0, stream>>>(Qb, Sb, e2part);
  k_build<<<B_ * 16, 256, 0, stream>>>(Qb, qv, qs_g, sum1, e2part, gamma, beta,
                                       Qs, qp_g);
  k_out<<<dim3(L_ / 128, C_ / 128, B_), 256, 0, stream>>>(Qs, qp_g, XbT, out);
}